// Round 5
// baseline (172.324 us; speedup 1.0000x reference)
//
#include <hip/hip_runtime.h>

// NSLayer: per 8x8 matrix x: A = I - x x^T (symmetric),
// out = (1+w7) x + sum_{k=1..7} w_{k-1} A^k x  via Horner on the vector.
//
// Decomposition: 2 lanes per matrix, lane h owns COLUMNS 4h..4h+3 of x/t/out
// and holds the FULL symmetric A (36 regs). Horner steps are shuffle-free.
//
// Row storage is half-permuted per lane: p<4 -> global row 4h+p,
// p>=4 -> global row 4(1-h)+(p-4). Partner's frame is mine composed with
// sigma(p)=p^4, so A[p][q] = delta - S[p][q] - shfl_xor(S[p^4][q^4], 1).
//
// Register-allocator saga:
//   R2: __launch_bounds__(256,4) -> VGPR cap 128, collapse to 64, scratch spill.
//   R3: __launch_bounds__(256,3) -> heuristic still targets 6 w/EU, VGPR 84,
//       64 floats/lane scratch spill (WRITE 192MB).
//   R4: waves_per_eu(2,4) -> target stays at max(4): VGPR 96 + 32KB/block
//       VGPR->LDS spill, 1.7e7 bank conflicts, occupancy capped by LDS.
//   Now: waves_per_eu(2,2) -> occupancy target = 2 waves/EU = 256-reg budget;
//       ~110 live values fit, no spill. 8 waves/CU suffices: each wave is
//       8 indep float4 loads + ~3800 cyc pure FMA + 8 stores.

__device__ __forceinline__ constexpr int sidx(int a, int b) {
    const int i = a < b ? a : b;
    const int k = a < b ? b : a;
    return i * 8 - i * (i + 1) / 2 + k;   // 0..35, upper-triangular packed
}

__global__ __launch_bounds__(256)
__attribute__((amdgpu_waves_per_eu(2, 2)))
void ns_poly_kernel(const float* __restrict__ in,
                    const float* __restrict__ wp,
                    float* __restrict__ out)
{
    const int tid = threadIdx.x;
    const int m   = blockIdx.x * 128 + (tid >> 1);   // matrix index
    const int h   = tid & 1;                          // column-half owner
    const bool hb = (h != 0);

    const float w0 = wp[0], w1 = wp[1], w2 = wp[2], w3 = wp[3];
    const float w4 = wp[4], w5 = wp[5], w6 = wp[6], w7 = wp[7];

    // ---- load own-half ROWS (16B vector loads), rows 4h..4h+3 ----
    const float* xm = in + (size_t)m * 64 + (size_t)h * 32;
    float xr[4][8];
#pragma unroll
    for (int r = 0; r < 4; ++r) {
        const float4 a = reinterpret_cast<const float4*>(xm)[2 * r];
        const float4 b = reinterpret_cast<const float4*>(xm)[2 * r + 1];
        xr[r][0] = a.x; xr[r][1] = a.y; xr[r][2] = a.z; xr[r][3] = a.w;
        xr[r][4] = b.x; xr[r][5] = b.y; xr[r][6] = b.z; xr[r][7] = b.w;
    }

    // ---- transpose to permuted column storage: xc[jj][p] = x[rho(p)][4h+jj] ----
    float xc[4][8];
#pragma unroll
    for (int p = 0; p < 4; ++p)
#pragma unroll
        for (int jj = 0; jj < 4; ++jj)
            xc[jj][p] = hb ? xr[p][4 + jj] : xr[p][jj];
#pragma unroll
    for (int r = 0; r < 4; ++r)
#pragma unroll
        for (int jj = 0; jj < 4; ++jj) {
            const float sv = hb ? xr[r][jj] : xr[r][4 + jj];
            xc[jj][4 + r] = __shfl_xor(sv, 1);
        }

    // ---- partial S = (x x^T restricted to my 4 columns), 36 packed ----
    float S[36];
#pragma unroll
    for (int p = 0; p < 8; ++p)
#pragma unroll
        for (int q = 0; q < 8; ++q) {
            if (q < p) continue;
            float s = xc[0][p] * xc[0][q];
            s += xc[1][p] * xc[1][q];
            s += xc[2][p] * xc[2][q];
            s += xc[3][p] * xc[3][q];
            S[sidx(p, q)] = s;
        }

    // ---- A = I - S - partner(S), consumed pairwise under sigma(p)=p^4 ----
    float A[36];
#pragma unroll
    for (int p = 0; p < 8; ++p)
#pragma unroll
        for (int q = 0; q < 8; ++q) {
            if (q < p) continue;
            const int e = sidx(p, q);
            const int f = sidx(p ^ 4, q ^ 4);
            if (e > f) continue;                       // partner of an earlier pair
            if (e == f) {                              // fixed point: q == p^4
                const float o = __shfl_xor(S[e], 1);
                A[e] = -S[e] - o;                      // p != q here, no delta
            } else {
                const float oa = __shfl_xor(S[f], 1);  // partner's value for entry e
                const float ob = __shfl_xor(S[e], 1);  // partner's value for entry f
                A[e] = (p == q ? 1.0f : 0.0f) - S[e] - oa;
                A[f] = (p == q ? 1.0f : 0.0f) - S[f] - ob;  // diag pairs with diag
            }
        }

    // ---- Horner: t = w6*x; t <- wk*x + A*t (shuffle-free) ----
    float t[4][8];
#pragma unroll
    for (int jj = 0; jj < 4; ++jj)
#pragma unroll
        for (int p = 0; p < 8; ++p)
            t[jj][p] = w6 * xc[jj][p];

    auto horner_step = [&](float wk) {
#pragma unroll
        for (int jj = 0; jj < 4; ++jj) {
            float s[8];
#pragma unroll
            for (int p = 0; p < 8; ++p)
                s[p] = wk * xc[jj][p];
#pragma unroll
            for (int q = 0; q < 8; ++q)
#pragma unroll
                for (int p = 0; p < 8; ++p)
                    s[p] += A[sidx(p, q)] * t[jj][q];
#pragma unroll
            for (int p = 0; p < 8; ++p)
                t[jj][p] = s[p];
        }
    };

    horner_step(w5);
    horner_step(w4);
    horner_step(w3);
    horner_step(w2);
    horner_step(w1);
    horner_step(w0);
    horner_step(1.0f + w7);   // t = (1+w7)*x + A*z0 = out columns

    // ---- transpose back and store own-half rows (16B vector stores) ----
    float rv[4][4];
#pragma unroll
    for (int jj = 0; jj < 4; ++jj)
#pragma unroll
        for (int r = 0; r < 4; ++r)
            rv[jj][r] = __shfl_xor(t[jj][4 + r], 1);   // out[4h+r][4(1-h)+jj]

    float* om = out + (size_t)m * 64 + (size_t)h * 32;
#pragma unroll
    for (int r = 0; r < 4; ++r) {
        float o[8];
#pragma unroll
        for (int c = 0; c < 4; ++c) {
            o[c]     = hb ? rv[c][r] : t[c][r];
            o[4 + c] = hb ? t[c][r] : rv[c][r];
        }
        reinterpret_cast<float4*>(om)[2 * r]     = make_float4(o[0], o[1], o[2], o[3]);
        reinterpret_cast<float4*>(om)[2 * r + 1] = make_float4(o[4], o[5], o[6], o[7]);
    }
}

extern "C" void kernel_launch(void* const* d_in, const int* in_sizes, int n_in,
                              void* d_out, int out_size, void* d_ws, size_t ws_size,
                              hipStream_t stream)
{
    const float* in = (const float*)d_in[0];
    const float* w  = (const float*)d_in[1];
    float* outp     = (float*)d_out;

    const int nmat   = in_sizes[0] / 64;   // 262144 matrices
    const int blocks = nmat / 128;         // 128 matrices per 256-thread block
    ns_poly_kernel<<<blocks, 256, 0, stream>>>(in, w, outp);
}

// Round 6
// 128.404 us; speedup vs baseline: 1.3420x; 1.3420x over previous
//
#include <hip/hip_runtime.h>

// NSLayer: per 8x8 matrix x: A = I - x x^T (symmetric),
// out = (1+w7) x + sum_{k=1..7} w_{k-1} A^k x  via Horner on the vector.
//
// Decomposition: 2 lanes per matrix, lane h owns COLUMNS 4h..4h+3 of x/t/out.
// Rows are stored half-permuted per lane: p<4 -> global row 4h+p,
// p>=4 -> global row 4(1-h)+(p-4).  Partner's frame is mine composed with
// sigma(p)=p^4, so the Gram reduction is one shfl_xor per entry:
//   G[p][q] = S[p][q] + shfl_xor(S[p^4][q^4], 1);  A = I - G.
// Horner steps (t <- wk*x + A*t) touch only the lane's own columns: NO
// shuffles. I/O transposes are done by ADDRESSING (strided float4 loads/
// stores of column fragments), not shuffles/selects.
//
// Code-shape lesson (R2-R5): sidx-packed triangular arrays + occupancy
// attributes made the backend demote state to scratch (R3: 192MB writes) or
// LDS (R4/R5: 32KB block, 1.7e7 bank conflicts, 64-way serialization).
// R1's plain [n][8] arrays + __launch_bounds__(256,2) compiled clean at
// 80 VGPR. So: plain 2-D arrays, upper-triangle writes only (dead elements
// SROA away), no packing, no waves_per_eu.

#define SE(p, q) S[(p) < (q) ? (p) : (q)][(p) < (q) ? (q) : (p)]
#define AE(p, q) A[(p) < (q) ? (p) : (q)][(p) < (q) ? (q) : (p)]

__global__ __launch_bounds__(256, 2)
void ns_poly_kernel(const float* __restrict__ in,
                    const float* __restrict__ wp,
                    float* __restrict__ out)
{
    const int tid = threadIdx.x;
    const int m   = blockIdx.x * 128 + (tid >> 1);   // matrix index
    const int h   = tid & 1;                          // column-half owner

    const float w0 = wp[0], w1 = wp[1], w2 = wp[2], w3 = wp[3];
    const float w4 = wp[4], w5 = wp[5], w6 = wp[6], w7 = wp[7];

    // ---- direct column-fragment loads (transpose by addressing) ----
    // my columns are at byte offset 16h in each row; own-half rows at
    // float offset h*32, partner-half rows at (1-h)*32.
    const float* bp      = in + (size_t)m * 64 + h * 4;
    const float* baseOwn = bp + h * 32;
    const float* basePar = bp + (1 - h) * 32;

    float xc[4][8];                                   // xc[jj][p]: col 4h+jj, permuted row p
#pragma unroll
    for (int p = 0; p < 4; ++p) {
        const float4 v = *reinterpret_cast<const float4*>(baseOwn + p * 8);
        xc[0][p] = v.x; xc[1][p] = v.y; xc[2][p] = v.z; xc[3][p] = v.w;
    }
#pragma unroll
    for (int p = 0; p < 4; ++p) {
        const float4 v = *reinterpret_cast<const float4*>(basePar + p * 8);
        xc[0][4 + p] = v.x; xc[1][4 + p] = v.y; xc[2][4 + p] = v.z; xc[3][4 + p] = v.w;
    }

    // ---- partial Gram S[p][q] = sum over my 4 columns (upper triangle) ----
    float S[8][8];
#pragma unroll
    for (int p = 0; p < 8; ++p)
#pragma unroll
        for (int q = p; q < 8; ++q) {
            float s = xc[0][p] * xc[0][q];
            s += xc[1][p] * xc[1][q];
            s += xc[2][p] * xc[2][q];
            s += xc[3][p] * xc[3][q];
            S[p][q] = s;
        }

    // ---- A = I - S - partner(S) (one shfl_xor per entry) ----
    float A[8][8];
#pragma unroll
    for (int p = 0; p < 8; ++p)
#pragma unroll
        for (int q = p; q < 8; ++q) {
            const float other = __shfl_xor(SE((p) ^ 4, (q) ^ 4), 1);
            A[p][q] = (p == q ? 1.0f : 0.0f) - S[p][q] - other;
        }

    // ---- Horner: t = w6*x; t <- wk*x + A*t (shuffle-free) ----
    float t[4][8];
#pragma unroll
    for (int jj = 0; jj < 4; ++jj)
#pragma unroll
        for (int p = 0; p < 8; ++p)
            t[jj][p] = w6 * xc[jj][p];

    auto horner_step = [&](float wk) {
#pragma unroll
        for (int jj = 0; jj < 4; ++jj) {
            float s[8];
#pragma unroll
            for (int p = 0; p < 8; ++p)
                s[p] = wk * xc[jj][p];
#pragma unroll
            for (int q = 0; q < 8; ++q)
#pragma unroll
                for (int p = 0; p < 8; ++p)
                    s[p] += AE(p, q) * t[jj][q];
#pragma unroll
            for (int p = 0; p < 8; ++p)
                t[jj][p] = s[p];
        }
    };

    horner_step(w5);
    horner_step(w4);
    horner_step(w3);
    horner_step(w2);
    horner_step(w1);
    horner_step(w0);
    horner_step(1.0f + w7);   // t = (1+w7)*x + A*z0 = out columns

    // ---- direct column-fragment stores (transpose by addressing) ----
    float* obp     = out + (size_t)m * 64 + h * 4;
    float* oandOwn = obp + h * 32;
    float* oandPar = obp + (1 - h) * 32;
#pragma unroll
    for (int p = 0; p < 4; ++p)
        *reinterpret_cast<float4*>(oandOwn + p * 8) =
            make_float4(t[0][p], t[1][p], t[2][p], t[3][p]);
#pragma unroll
    for (int p = 0; p < 4; ++p)
        *reinterpret_cast<float4*>(oandPar + p * 8) =
            make_float4(t[0][4 + p], t[1][4 + p], t[2][4 + p], t[3][4 + p]);
}

extern "C" void kernel_launch(void* const* d_in, const int* in_sizes, int n_in,
                              void* d_out, int out_size, void* d_ws, size_t ws_size,
                              hipStream_t stream)
{
    const float* in = (const float*)d_in[0];
    const float* w  = (const float*)d_in[1];
    float* outp     = (float*)d_out;

    const int nmat   = in_sizes[0] / 64;   // 262144 matrices
    const int blocks = nmat / 128;         // 128 matrices per 256-thread block
    ns_poly_kernel<<<blocks, 256, 0, stream>>>(in, w, outp);
}